// Round 2
// baseline (814.162 us; speedup 1.0000x reference)
//
#include <hip/hip_runtime.h>

typedef float    f32x4 __attribute__((ext_vector_type(4)));
typedef short    s16x8 __attribute__((ext_vector_type(8)));
typedef short    s16x4 __attribute__((ext_vector_type(4)));
typedef _Float16 h16x4 __attribute__((ext_vector_type(4)));

#define DEV __device__ __forceinline__

// fp32 -> bf16, round-to-nearest-even (finite inputs only)
DEV short f2bf(float f) {
  unsigned u = __builtin_bit_cast(unsigned, f);
  u += 0x7fffu + ((u >> 16) & 1u);
  return (short)(u >> 16);
}
DEV float bf2f(short s) {
  unsigned u = ((unsigned)(unsigned short)s) << 16;
  return __builtin_bit_cast(float, u);
}

// async global -> LDS, 16 bytes per lane; LDS dest = wave-uniform base + lane*16
DEV void async_load16(const void* g, void* l) {
  __builtin_amdgcn_global_load_lds((const __attribute__((address_space(1))) void*)g,
                                   (__attribute__((address_space(3))) void*)l,
                                   16, 0, 0);
}

// ---------------------------------------------------------------------------
// Plain bf16 GEMM: C[16384,1024] = A[16384,1024] @ Bw[1024,1024]^T + bias
// (used for V projection and the output projection)
// ---------------------------------------------------------------------------
template <bool AF32, bool OF32>
DEV void gemm128(const void* Av, const short* __restrict__ Bw,
                 const float* __restrict__ bias, void* Cv) {
  constexpr int K = 1024, N = 1024;
  __shared__ __align__(16) short As[128 * 32];
  __shared__ __align__(16) short Bs[128 * 32];

  const int tid  = threadIdx.x;
  const int lane = tid & 63;
  const int w    = tid >> 6;
  const int bm   = blockIdx.x >> 3;
  const int bn   = blockIdx.x & 7;
  const int rowbase = bm << 7;
  const int colbase = bn << 7;
  const int wm = w >> 1, wn = w & 1;
  const int m16 = lane & 15, q = lane >> 4;

  f32x4 acc[4][4];
#pragma unroll
  for (int nt = 0; nt < 4; ++nt) {
    const float bv = bias[colbase + wn * 64 + nt * 16 + m16];
#pragma unroll
    for (int mt = 0; mt < 4; ++mt) acc[mt][nt] = {bv, bv, bv, bv};
  }

  const int brow = (lane >> 2);
  const int bcol = (lane & 3) * 8;

  for (int ki = 0; ki < 32; ++ki) {
    const int k0 = ki * 32;
    if constexpr (AF32) {
      const float* A = (const float*)Av;
#pragma unroll
      for (int i = 0; i < 4; ++i) {
        const int f = tid + i * 256;
        const int r = f >> 3, c4 = f & 7;
        const float4 v = *(const float4*)(A + (size_t)(rowbase + r) * K + k0 + c4 * 4);
        s16x4 o = {f2bf(v.x), f2bf(v.y), f2bf(v.z), f2bf(v.w)};
        *(s16x4*)&As[r * 32 + c4 * 4] = o;
      }
    } else {
      const short* A = (const short*)Av;
#pragma unroll
      for (int i = 0; i < 2; ++i) {
        const int f = tid + i * 256;
        const int r = f >> 2, c8 = f & 3;
        *(s16x8*)&As[r * 32 + c8 * 8] =
            *(const s16x8*)(A + (size_t)(rowbase + r) * K + k0 + c8 * 8);
      }
    }
#pragma unroll
    for (int t = 0; t < 2; ++t) {
      const short* g = Bw + (size_t)(colbase + (w * 2 + t) * 16 + brow) * K + k0 + bcol;
      async_load16(g, &Bs[(w * 2 + t) * 512]);
    }
    __syncthreads();

    s16x8 af[4], bfr[4];
#pragma unroll
    for (int mt = 0; mt < 4; ++mt)
      af[mt] = *(const s16x8*)&As[(wm * 64 + mt * 16 + m16) * 32 + q * 8];
#pragma unroll
    for (int nt = 0; nt < 4; ++nt)
      bfr[nt] = *(const s16x8*)&Bs[(wn * 64 + nt * 16 + m16) * 32 + q * 8];
#pragma unroll
    for (int mt = 0; mt < 4; ++mt)
#pragma unroll
      for (int nt = 0; nt < 4; ++nt)
        acc[mt][nt] = __builtin_amdgcn_mfma_f32_16x16x32_bf16(af[mt], bfr[nt], acc[mt][nt], 0, 0, 0);
    __syncthreads();
  }

#pragma unroll
  for (int mt = 0; mt < 4; ++mt) {
#pragma unroll
    for (int nt = 0; nt < 4; ++nt) {
      const int col = colbase + wn * 64 + nt * 16 + m16;
#pragma unroll
      for (int r = 0; r < 4; ++r) {
        const int row = rowbase + wm * 64 + mt * 16 + q * 4 + r;
        if constexpr (OF32)
          ((float*)Cv)[(size_t)row * N + col] = acc[mt][nt][r];
        else
          ((short*)Cv)[(size_t)row * N + col] = f2bf(acc[mt][nt][r]);
      }
    }
  }
}

// ---------------------------------------------------------------------------
// Split-precision GEMM for Q and K: A = Ah + Al, W = Wh + Wl (bf16 pairs),
// acc = Ah*Wh + Ah*Wl + Al*Wh (fp32 accum). q,k relative error ~3e-5.
// Output fp16.
// ---------------------------------------------------------------------------
__global__ __launch_bounds__(256) void k_gemm_qk(
    const float* __restrict__ Aq, const float* __restrict__ Ak,
    const short* __restrict__ Wqh, const short* __restrict__ Wql,
    const short* __restrict__ Wkh, const short* __restrict__ Wkl,
    const float* __restrict__ bq, const float* __restrict__ bk,
    _Float16* __restrict__ outbase) {
  constexpr int K = 1024, N = 1024;
  const int y = blockIdx.y;
  const float* A    = y ? Ak  : Aq;
  const short* Bh   = y ? Wkh : Wqh;
  const short* Bl   = y ? Wkl : Wql;
  const float* bias = y ? bk  : bq;
  _Float16* C = outbase + (size_t)y * (16384 * 1024);

  __shared__ __align__(16) short Ah[128 * 32];
  __shared__ __align__(16) short Al[128 * 32];
  __shared__ __align__(16) short Bhs[128 * 32];
  __shared__ __align__(16) short Bls[128 * 32];

  const int tid  = threadIdx.x;
  const int lane = tid & 63;
  const int w    = tid >> 6;
  const int bm   = blockIdx.x >> 3;
  const int bn   = blockIdx.x & 7;
  const int rowbase = bm << 7;
  const int colbase = bn << 7;
  const int wm = w >> 1, wn = w & 1;
  const int m16 = lane & 15, q = lane >> 4;

  f32x4 acc[4][4];
#pragma unroll
  for (int nt = 0; nt < 4; ++nt) {
    const float bv = bias[colbase + wn * 64 + nt * 16 + m16];
#pragma unroll
    for (int mt = 0; mt < 4; ++mt) acc[mt][nt] = {bv, bv, bv, bv};
  }

  const int brow = (lane >> 2);
  const int bcol = (lane & 3) * 8;

  for (int ki = 0; ki < 32; ++ki) {
    const int k0 = ki * 32;
    // stage A: fp32 -> (hi, lo) bf16 pair
#pragma unroll
    for (int i = 0; i < 4; ++i) {
      const int f = tid + i * 256;
      const int r = f >> 3, c4 = f & 7;
      const float4 v = *(const float4*)(A + (size_t)(rowbase + r) * K + k0 + c4 * 4);
      s16x4 h, l;
      const float vv[4] = {v.x, v.y, v.z, v.w};
#pragma unroll
      for (int e = 0; e < 4; ++e) {
        h[e] = f2bf(vv[e]);
        l[e] = f2bf(vv[e] - bf2f(h[e]));  // exact residual (Sterbenz)
      }
      *(s16x4*)&Ah[r * 32 + c4 * 4] = h;
      *(s16x4*)&Al[r * 32 + c4 * 4] = l;
    }
    // stage B hi & lo tiles via async 16B loads
#pragma unroll
    for (int t = 0; t < 2; ++t) {
      const size_t go = (size_t)(colbase + (w * 2 + t) * 16 + brow) * K + k0 + bcol;
      async_load16(Bh + go, &Bhs[(w * 2 + t) * 512]);
      async_load16(Bl + go, &Bls[(w * 2 + t) * 512]);
    }
    __syncthreads();

    s16x8 ah[4], al[4], bh[4], bl[4];
#pragma unroll
    for (int mt = 0; mt < 4; ++mt) {
      const int off = (wm * 64 + mt * 16 + m16) * 32 + q * 8;
      ah[mt] = *(const s16x8*)&Ah[off];
      al[mt] = *(const s16x8*)&Al[off];
    }
#pragma unroll
    for (int nt = 0; nt < 4; ++nt) {
      const int off = (wn * 64 + nt * 16 + m16) * 32 + q * 8;
      bh[nt] = *(const s16x8*)&Bhs[off];
      bl[nt] = *(const s16x8*)&Bls[off];
    }
#pragma unroll
    for (int mt = 0; mt < 4; ++mt)
#pragma unroll
      for (int nt = 0; nt < 4; ++nt) {
        acc[mt][nt] = __builtin_amdgcn_mfma_f32_16x16x32_bf16(ah[mt], bh[nt], acc[mt][nt], 0, 0, 0);
        acc[mt][nt] = __builtin_amdgcn_mfma_f32_16x16x32_bf16(ah[mt], bl[nt], acc[mt][nt], 0, 0, 0);
        acc[mt][nt] = __builtin_amdgcn_mfma_f32_16x16x32_bf16(al[mt], bh[nt], acc[mt][nt], 0, 0, 0);
      }
    __syncthreads();
  }

#pragma unroll
  for (int mt = 0; mt < 4; ++mt) {
#pragma unroll
    for (int nt = 0; nt < 4; ++nt) {
      const int col = colbase + wn * 64 + nt * 16 + m16;
#pragma unroll
      for (int r = 0; r < 4; ++r) {
        const int row = rowbase + wm * 64 + mt * 16 + q * 4 + r;
        C[(size_t)row * N + col] = (_Float16)acc[mt][nt][r];
      }
    }
  }
}

// weights fp32 -> bf16 (hi/lo pairs for Wq,Wk; single for Wv,Wo)
__global__ __launch_bounds__(256) void k_cvt_w(const float* __restrict__ Wq,
                                               const float* __restrict__ Wk,
                                               const float* __restrict__ Wv,
                                               const float* __restrict__ Wo,
                                               short* __restrict__ Wqh, short* __restrict__ Wql,
                                               short* __restrict__ Wkh, short* __restrict__ Wkl,
                                               short* __restrict__ Wvb, short* __restrict__ Wob) {
  const float* src;
  short *dh, *dl = nullptr;
  switch (blockIdx.y) {
    case 0: src = Wq; dh = Wqh; dl = Wql; break;
    case 1: src = Wk; dh = Wkh; dl = Wkl; break;
    case 2: src = Wv; dh = Wvb; break;
    default: src = Wo; dh = Wob; break;
  }
  const int idx = blockIdx.x * 256 + threadIdx.x;  // float4 index
  const float4 v = ((const float4*)src)[idx];
  const float vv[4] = {v.x, v.y, v.z, v.w};
  s16x4 h, l;
#pragma unroll
  for (int e = 0; e < 4; ++e) {
    h[e] = f2bf(vv[e]);
    l[e] = f2bf(vv[e] - bf2f(h[e]));
  }
  ((s16x4*)dh)[idx] = h;
  if (dl) ((s16x4*)dl)[idx] = l;
}

__global__ __launch_bounds__(256) void k_gemm_v(const float* __restrict__ v,
                                                const short* __restrict__ Wvb,
                                                const float* __restrict__ bv,
                                                short* __restrict__ out) {
  gemm128<true, false>(v, Wvb, bv, out);
}

__global__ __launch_bounds__(256) void k_gemm_out(const short* __restrict__ A,
                                                  const short* __restrict__ Wob,
                                                  const float* __restrict__ bo,
                                                  float* __restrict__ C) {
  gemm128<false, true>(A, Wob, bo, C);
}

// ---------------------------------------------------------------------------
// Per-position local attention. q,k fp16; v bf16. fp32 math throughout.
// ---------------------------------------------------------------------------
__global__ __launch_bounds__(256) void k_attn(const _Float16* __restrict__ qp,
                                              const _Float16* __restrict__ kp,
                                              const short* __restrict__ vp,
                                              short* __restrict__ op) {
  __shared__ float qs[64 * 16], ks[64 * 16], vs[64 * 16];
  const int tid = threadIdx.x;
  const size_t base = (size_t)blockIdx.x * 1024;
  {
    const int d0 = tid * 4;
    h16x4 a = *(const h16x4*)(qp + base + d0);
    h16x4 b = *(const h16x4*)(kp + base + d0);
    s16x4 c = *(const s16x4*)(vp + base + d0);
#pragma unroll
    for (int e = 0; e < 4; ++e) {
      qs[d0 + e] = (float)a[e];
      ks[d0 + e] = (float)b[e];
      vs[d0 + e] = bf2f(c[e]);
    }
  }
  __syncthreads();

  const int i  = tid >> 2;
  const int qd = tid & 3;
  const int j0 = qd * 16;

  float qreg[16];
#pragma unroll
  for (int c = 0; c < 4; ++c) {
    const float4 t = *(const float4*)&qs[i * 16 + c * 4];
    qreg[c * 4 + 0] = t.x; qreg[c * 4 + 1] = t.y;
    qreg[c * 4 + 2] = t.z; qreg[c * 4 + 3] = t.w;
  }

  float s[16];
  float mx = -3.0e38f;
#pragma unroll
  for (int jj = 0; jj < 16; ++jj) {
    const int j = j0 + jj;
    float a = 0.f;
#pragma unroll
    for (int c = 0; c < 4; ++c) {
      const float4 kv = *(const float4*)&ks[j * 16 + c * 4];
      a += qreg[c * 4 + 0] * kv.x + qreg[c * 4 + 1] * kv.y +
           qreg[c * 4 + 2] * kv.z + qreg[c * 4 + 3] * kv.w;
    }
    s[jj] = a * 32.0f;  // reference multiplies by sqrt(D)=32
    mx = fmaxf(mx, s[jj]);
  }
  mx = fmaxf(mx, __shfl_xor(mx, 1));
  mx = fmaxf(mx, __shfl_xor(mx, 2));

  float sum = 0.f;
#pragma unroll
  for (int jj = 0; jj < 16; ++jj) {
    s[jj] = __expf(s[jj] - mx);
    sum += s[jj];
  }
  sum += __shfl_xor(sum, 1);
  sum += __shfl_xor(sum, 2);
  const float inv = 1.0f / sum;

  float o[16];
#pragma unroll
  for (int h = 0; h < 16; ++h) o[h] = 0.f;
#pragma unroll
  for (int jj = 0; jj < 16; ++jj) {
    const float p = s[jj];
    const int j = j0 + jj;
#pragma unroll
    for (int c = 0; c < 4; ++c) {
      const float4 vv = *(const float4*)&vs[j * 16 + c * 4];
      o[c * 4 + 0] += p * vv.x; o[c * 4 + 1] += p * vv.y;
      o[c * 4 + 2] += p * vv.z; o[c * 4 + 3] += p * vv.w;
    }
  }
#pragma unroll
  for (int h = 0; h < 16; ++h) {
    o[h] += __shfl_xor(o[h], 1);
    o[h] += __shfl_xor(o[h], 2);
  }
  s16x4 wv;
#pragma unroll
  for (int c = 0; c < 4; ++c) wv[c] = f2bf(o[qd * 4 + c] * inv);
  *(s16x4*)(op + base + i * 16 + qd * 4) = wv;
}

extern "C" void kernel_launch(void* const* d_in, const int* in_sizes, int n_in,
                              void* d_out, int out_size, void* d_ws, size_t ws_size,
                              hipStream_t stream) {
  const float* query = (const float*)d_in[0];
  const float* key_  = (const float*)d_in[1];
  const float* value = (const float*)d_in[2];
  const float* Wq    = (const float*)d_in[3];
  const float* bq    = (const float*)d_in[4];
  const float* Wk    = (const float*)d_in[5];
  const float* bk    = (const float*)d_in[6];
  const float* Wv    = (const float*)d_in[7];
  const float* bv    = (const float*)d_in[8];
  const float* Wo    = (const float*)d_in[9];
  const float* bo    = (const float*)d_in[10];

  constexpr size_t MW = 1024 * 1024;          // one weight matrix (elements)
  constexpr size_t MA = (size_t)16384 * 1024; // one activation matrix (elements)

  char* ws = (char*)d_ws;
  short* Wqh = (short*)ws;                    // 6 bf16 weight matrices: 12 MB
  short* Wql = Wqh + MW;
  short* Wkh = Wql + MW;
  short* Wkl = Wkh + MW;
  short* Wvb = Wkl + MW;
  short* Wob = Wvb + MW;
  _Float16* qk = (_Float16*)(Wob + MW);       // q,k fp16: 64 MB
  short* vbf = (short*)(qk + 2 * MA);         // v bf16: 32 MB
  short* ao  = vbf + MA;                      // attn out bf16: 32 MB  (total 140 MB)

  k_cvt_w<<<dim3(1024, 4), 256, 0, stream>>>(Wq, Wk, Wv, Wo,
                                             Wqh, Wql, Wkh, Wkl, Wvb, Wob);
  k_gemm_qk<<<dim3(1024, 2), 256, 0, stream>>>(query, key_, Wqh, Wql, Wkh, Wkl,
                                               bq, bk, qk);
  k_gemm_v<<<1024, 256, 0, stream>>>(value, Wvb, bv, vbf);
  k_attn<<<16384, 256, 0, stream>>>(qk, qk + MA, vbf, ao);
  k_gemm_out<<<1024, 256, 0, stream>>>(ao, Wob, bo, (float*)d_out);
}

// Round 3
// 689.214 us; speedup vs baseline: 1.1813x; 1.1813x over previous
//
#include <hip/hip_runtime.h>

typedef float    f32x4 __attribute__((ext_vector_type(4)));
typedef _Float16 h16x8 __attribute__((ext_vector_type(8)));
typedef _Float16 h16x4 __attribute__((ext_vector_type(4)));

#define DEV __device__ __forceinline__

// async global -> LDS, 16 bytes per lane; LDS dest = wave-uniform base + lane*16
DEV void async_load16(const void* g, void* l) {
  __builtin_amdgcn_global_load_lds((const __attribute__((address_space(1))) void*)g,
                                   (__attribute__((address_space(3))) void*)l,
                                   16, 0, 0);
}

// ---------------------------------------------------------------------------
// Unified fp16 GEMM: C[16384,1024] = A[16384,1024] @ Bw[1024,1024]^T + bias
// AMODE 0: A fp16, async-staged.  AMODE 1: A fp32, convert during staging.
// 128x128 block tile, BK=32, 4 waves x (4x4) mfma_f32_16x16x32_f16.
// grid.x = 1024: blockIdx.x>>3 = m-tile, &7 = n-tile.
// ---------------------------------------------------------------------------
template <int AMODE, bool OF32>
DEV void gemm_core(const void* Av, const _Float16* __restrict__ Bw,
                   const float* __restrict__ bias, void* Cv) {
  constexpr int K = 1024, N = 1024;
  __shared__ __align__(16) _Float16 As[128 * 32];
  __shared__ __align__(16) _Float16 Bs[128 * 32];

  const int tid  = threadIdx.x;
  const int lane = tid & 63;
  const int w    = tid >> 6;
  const int bm   = blockIdx.x >> 3;
  const int bn   = blockIdx.x & 7;
  const int rowbase = bm << 7;
  const int colbase = bn << 7;
  const int wm = w >> 1, wn = w & 1;
  const int m16 = lane & 15, q = lane >> 4;
  const int brow = lane >> 2;        // row within a 16-row chunk
  const int bcol = (lane & 3) * 8;   // k offset (8 fp16 = 16B)

  f32x4 acc[4][4];
#pragma unroll
  for (int nt = 0; nt < 4; ++nt) {
    const float bv = bias[colbase + wn * 64 + nt * 16 + m16];
#pragma unroll
    for (int mt = 0; mt < 4; ++mt) acc[mt][nt] = {bv, bv, bv, bv};
  }

  for (int ki = 0; ki < 32; ++ki) {
    const int k0 = ki * 32;
    // ---- stage A tile (128x32 fp16) ----
    if constexpr (AMODE == 0) {
      const _Float16* A = (const _Float16*)Av;
#pragma unroll
      for (int t = 0; t < 2; ++t)
        async_load16(A + (size_t)(rowbase + (w * 2 + t) * 16 + brow) * K + k0 + bcol,
                     &As[(w * 2 + t) * 512]);
    } else {
      const float* A = (const float*)Av;
#pragma unroll
      for (int i = 0; i < 4; ++i) {
        const int f = tid + i * 256;
        const int r = f >> 3, c4 = f & 7;
        const float4 v = *(const float4*)(A + (size_t)(rowbase + r) * K + k0 + c4 * 4);
        h16x4 o = {(_Float16)v.x, (_Float16)v.y, (_Float16)v.z, (_Float16)v.w};
        *(h16x4*)&As[r * 32 + c4 * 4] = o;
      }
    }
    // ---- stage B tile (128x32 fp16) ----
#pragma unroll
    for (int t = 0; t < 2; ++t)
      async_load16(Bw + (size_t)(colbase + (w * 2 + t) * 16 + brow) * K + k0 + bcol,
                   &Bs[(w * 2 + t) * 512]);
    __syncthreads();

    h16x8 af[4], bfr[4];
#pragma unroll
    for (int mt = 0; mt < 4; ++mt)
      af[mt] = *(const h16x8*)&As[(wm * 64 + mt * 16 + m16) * 32 + q * 8];
#pragma unroll
    for (int nt = 0; nt < 4; ++nt)
      bfr[nt] = *(const h16x8*)&Bs[(wn * 64 + nt * 16 + m16) * 32 + q * 8];
#pragma unroll
    for (int mt = 0; mt < 4; ++mt)
#pragma unroll
      for (int nt = 0; nt < 4; ++nt)
        acc[mt][nt] = __builtin_amdgcn_mfma_f32_16x16x32_f16(af[mt], bfr[nt], acc[mt][nt], 0, 0, 0);
    __syncthreads();
  }

  // ---- epilogue: C/D layout col = lane&15, row = q*4 + reg ----
#pragma unroll
  for (int mt = 0; mt < 4; ++mt) {
#pragma unroll
    for (int nt = 0; nt < 4; ++nt) {
      const int col = colbase + wn * 64 + nt * 16 + m16;
#pragma unroll
      for (int r = 0; r < 4; ++r) {
        const int row = rowbase + wm * 64 + mt * 16 + q * 4 + r;
        if constexpr (OF32)
          ((float*)Cv)[(size_t)row * N + col] = acc[mt][nt][r];
        else
          ((_Float16*)Cv)[(size_t)row * N + col] = (_Float16)acc[mt][nt][r];
      }
    }
  }
}

// weights fp32 -> fp16 (4 matrices of 1024x1024, contiguous dst)
__global__ __launch_bounds__(256) void k_cvt_w(const float* __restrict__ Wq,
                                               const float* __restrict__ Wk,
                                               const float* __restrict__ Wv,
                                               const float* __restrict__ Wo,
                                               _Float16* __restrict__ dst) {
  const float* src;
  switch (blockIdx.y) {
    case 0: src = Wq; break;
    case 1: src = Wk; break;
    case 2: src = Wv; break;
    default: src = Wo; break;
  }
  _Float16* d = dst + (size_t)blockIdx.y * (1024 * 1024);
  const int idx = blockIdx.x * 256 + threadIdx.x;  // float4 index, 262144 total
  const float4 v = ((const float4*)src)[idx];
  h16x4 o = {(_Float16)v.x, (_Float16)v.y, (_Float16)v.z, (_Float16)v.w};
  ((h16x4*)d)[idx] = o;
}

// activations fp32 -> fp16 (3 matrices of 16384x1024, contiguous dst)
__global__ __launch_bounds__(256) void k_cvt_a(const float* __restrict__ q,
                                               const float* __restrict__ k,
                                               const float* __restrict__ v,
                                               _Float16* __restrict__ dst) {
  const float* src = (blockIdx.y == 0) ? q : (blockIdx.y == 1) ? k : v;
  _Float16* d = dst + (size_t)blockIdx.y * ((size_t)16384 * 1024);
  const size_t idx = (size_t)blockIdx.x * 256 + threadIdx.x;  // float4 index, 4M total
  const float4 vv = ((const float4*)src)[idx];
  h16x4 o = {(_Float16)vv.x, (_Float16)vv.y, (_Float16)vv.z, (_Float16)vv.w};
  ((h16x4*)d)[idx] = o;
}

__global__ __launch_bounds__(256) void k_gemm_qkv_f16(const _Float16* __restrict__ xf,
                                                      const _Float16* __restrict__ Wf,
                                                      const float* __restrict__ bq,
                                                      const float* __restrict__ bk,
                                                      const float* __restrict__ bv,
                                                      _Float16* __restrict__ proj) {
  constexpr size_t MW = 1024 * 1024, MA = (size_t)16384 * 1024;
  const int y = blockIdx.y;
  const float* bias = (y == 0) ? bq : (y == 1) ? bk : bv;
  gemm_core<0, false>(xf + y * MA, Wf + y * MW, bias, proj + y * MA);
}

__global__ __launch_bounds__(256) void k_gemm_qkv_f32(const float* __restrict__ q,
                                                      const float* __restrict__ k,
                                                      const float* __restrict__ v,
                                                      const _Float16* __restrict__ Wf,
                                                      const float* __restrict__ bq,
                                                      const float* __restrict__ bk,
                                                      const float* __restrict__ bv,
                                                      _Float16* __restrict__ proj) {
  constexpr size_t MW = 1024 * 1024, MA = (size_t)16384 * 1024;
  const int y = blockIdx.y;
  const float* A    = (y == 0) ? q  : (y == 1) ? k  : v;
  const float* bias = (y == 0) ? bq : (y == 1) ? bk : bv;
  gemm_core<1, false>(A, Wf + y * MW, bias, proj + y * MA);
}

__global__ __launch_bounds__(256) void k_gemm_out(const _Float16* __restrict__ ao,
                                                  const _Float16* __restrict__ Wof,
                                                  const float* __restrict__ bo,
                                                  float* __restrict__ C) {
  gemm_core<0, true>(ao, Wof, bo, C);
}

// ---------------------------------------------------------------------------
// Per-position local attention, all fp16 I/O, fp32 math.
// One block per (b,l); thread (i = tid>>2, qd = tid&3) owns j in [qd*16, +16).
// ---------------------------------------------------------------------------
__global__ __launch_bounds__(256) void k_attn(const _Float16* __restrict__ qp,
                                              const _Float16* __restrict__ kp,
                                              const _Float16* __restrict__ vp,
                                              _Float16* __restrict__ op) {
  __shared__ float qs[64 * 16], ks[64 * 16], vs[64 * 16];
  const int tid = threadIdx.x;
  const size_t base = (size_t)blockIdx.x * 1024;
  {
    const int d0 = tid * 4;
    h16x4 a = *(const h16x4*)(qp + base + d0);
    h16x4 b = *(const h16x4*)(kp + base + d0);
    h16x4 c = *(const h16x4*)(vp + base + d0);
#pragma unroll
    for (int e = 0; e < 4; ++e) {
      qs[d0 + e] = (float)a[e];
      ks[d0 + e] = (float)b[e];
      vs[d0 + e] = (float)c[e];
    }
  }
  __syncthreads();

  const int i  = tid >> 2;
  const int qd = tid & 3;
  const int j0 = qd * 16;

  float qreg[16];
#pragma unroll
  for (int c = 0; c < 4; ++c) {
    const float4 t = *(const float4*)&qs[i * 16 + c * 4];
    qreg[c * 4 + 0] = t.x; qreg[c * 4 + 1] = t.y;
    qreg[c * 4 + 2] = t.z; qreg[c * 4 + 3] = t.w;
  }

  float s[16];
  float mx = -3.0e38f;
#pragma unroll
  for (int jj = 0; jj < 16; ++jj) {
    const int j = j0 + jj;
    float a = 0.f;
#pragma unroll
    for (int c = 0; c < 4; ++c) {
      const float4 kv = *(const float4*)&ks[j * 16 + c * 4];
      a += qreg[c * 4 + 0] * kv.x + qreg[c * 4 + 1] * kv.y +
           qreg[c * 4 + 2] * kv.z + qreg[c * 4 + 3] * kv.w;
    }
    s[jj] = a * 32.0f;  // reference multiplies by sqrt(D)=32
    mx = fmaxf(mx, s[jj]);
  }
  mx = fmaxf(mx, __shfl_xor(mx, 1));
  mx = fmaxf(mx, __shfl_xor(mx, 2));

  float sum = 0.f;
#pragma unroll
  for (int jj = 0; jj < 16; ++jj) {
    s[jj] = __expf(s[jj] - mx);
    sum += s[jj];
  }
  sum += __shfl_xor(sum, 1);
  sum += __shfl_xor(sum, 2);
  const float inv = 1.0f / sum;

  float o[16];
#pragma unroll
  for (int h = 0; h < 16; ++h) o[h] = 0.f;
#pragma unroll
  for (int jj = 0; jj < 16; ++jj) {
    const float p = s[jj];
    const int j = j0 + jj;
#pragma unroll
    for (int c = 0; c < 4; ++c) {
      const float4 vv = *(const float4*)&vs[j * 16 + c * 4];
      o[c * 4 + 0] += p * vv.x; o[c * 4 + 1] += p * vv.y;
      o[c * 4 + 2] += p * vv.z; o[c * 4 + 3] += p * vv.w;
    }
  }
#pragma unroll
  for (int h = 0; h < 16; ++h) {
    o[h] += __shfl_xor(o[h], 1);
    o[h] += __shfl_xor(o[h], 2);
  }
  h16x4 wv;
#pragma unroll
  for (int c = 0; c < 4; ++c) wv[c] = (_Float16)(o[qd * 4 + c] * inv);
  *(h16x4*)(op + base + i * 16 + qd * 4) = wv;
}

extern "C" void kernel_launch(void* const* d_in, const int* in_sizes, int n_in,
                              void* d_out, int out_size, void* d_ws, size_t ws_size,
                              hipStream_t stream) {
  const float* query = (const float*)d_in[0];
  const float* key_  = (const float*)d_in[1];
  const float* value = (const float*)d_in[2];
  const float* Wq    = (const float*)d_in[3];
  const float* bq    = (const float*)d_in[4];
  const float* Wk    = (const float*)d_in[5];
  const float* bk    = (const float*)d_in[6];
  const float* Wv    = (const float*)d_in[7];
  const float* bv    = (const float*)d_in[8];
  const float* Wo    = (const float*)d_in[9];
  const float* bo    = (const float*)d_in[10];

  constexpr size_t MW = 1024 * 1024;          // one weight matrix (elements)
  constexpr size_t MA = (size_t)16384 * 1024; // one activation matrix (elements)

  _Float16* Wf = (_Float16*)d_ws;             // 4*MW fp16 = 8 MB

  // Path A needs: 4*MW (weights) + 3*MA (converted inputs) + 3*MA (projections),
  // all fp16; ao aliases the (dead-by-then) converted-input buffer.
  const size_t needA = (4 * MW + 6 * MA) * sizeof(_Float16);  // 200 MB

  k_cvt_w<<<dim3(1024, 4), 256, 0, stream>>>(Wq, Wk, Wv, Wo, Wf);

  if (ws_size >= needA) {
    _Float16* xf   = Wf + 4 * MW;       // converted q,k,v inputs: 96 MB
    _Float16* proj = xf + 3 * MA;       // projected q,k,v: 96 MB
    _Float16* ao   = xf;                // alias: inputs dead after QKV GEMM
    k_cvt_a<<<dim3(16384, 3), 256, 0, stream>>>(query, key_, value, xf);
    k_gemm_qkv_f16<<<dim3(1024, 3), 256, 0, stream>>>(xf, Wf, bq, bk, bv, proj);
    k_attn<<<16384, 256, 0, stream>>>(proj, proj + MA, proj + 2 * MA, ao);
    k_gemm_out<<<1024, 256, 0, stream>>>(ao, Wf + 3 * MW, bo, (float*)d_out);
  } else {
    _Float16* proj = Wf + 4 * MW;       // 96 MB
    _Float16* ao   = proj + 3 * MA;     // 32 MB (total 136 MB)
    k_gemm_qkv_f32<<<dim3(1024, 3), 256, 0, stream>>>(query, key_, value, Wf,
                                                      bq, bk, bv, proj);
    k_attn<<<16384, 256, 0, stream>>>(proj, proj + MA, proj + 2 * MA, ao);
    k_gemm_out<<<1024, 256, 0, stream>>>(ao, Wf + 3 * MW, bo, (float*)d_out);
  }
}

// Round 4
// 521.527 us; speedup vs baseline: 1.5611x; 1.3215x over previous
//
#include <hip/hip_runtime.h>

typedef float    f32x4 __attribute__((ext_vector_type(4)));
typedef _Float16 h16x8 __attribute__((ext_vector_type(8)));
typedef _Float16 h16x4 __attribute__((ext_vector_type(4)));

#define DEV __device__ __forceinline__

// async global -> LDS, 16 bytes per lane; LDS dest = wave-uniform base + lane*16
DEV void async_load16(const void* g, void* l) {
  __builtin_amdgcn_global_load_lds((const __attribute__((address_space(1))) void*)g,
                                   (__attribute__((address_space(3))) void*)l,
                                   16, 0, 0);
}

// ---------------------------------------------------------------------------
// Unified fp16 GEMM: C[16384,1024] = A[16384,1024] @ Bw[1024,1024]^T + bias
// AMODE 0: A fp16, async-staged.  AMODE 1: A fp32, convert during staging.
// 128x128 block tile, BK=32, 4 waves x (4x4) mfma_f32_16x16x32_f16.
// ---------------------------------------------------------------------------
template <int AMODE, bool OF32>
DEV void gemm_core(const void* Av, const _Float16* __restrict__ Bw,
                   const float* __restrict__ bias, void* Cv) {
  constexpr int K = 1024, N = 1024;
  __shared__ __align__(16) _Float16 As[128 * 32];
  __shared__ __align__(16) _Float16 Bs[128 * 32];

  const int tid  = threadIdx.x;
  const int lane = tid & 63;
  const int w    = tid >> 6;
  const int bm   = blockIdx.x >> 3;
  const int bn   = blockIdx.x & 7;
  const int rowbase = bm << 7;
  const int colbase = bn << 7;
  const int wm = w >> 1, wn = w & 1;
  const int m16 = lane & 15, q = lane >> 4;
  const int brow = lane >> 2;
  const int bcol = (lane & 3) * 8;

  f32x4 acc[4][4];
#pragma unroll
  for (int nt = 0; nt < 4; ++nt) {
    const float bv = bias[colbase + wn * 64 + nt * 16 + m16];
#pragma unroll
    for (int mt = 0; mt < 4; ++mt) acc[mt][nt] = {bv, bv, bv, bv};
  }

  for (int ki = 0; ki < 32; ++ki) {
    const int k0 = ki * 32;
    if constexpr (AMODE == 0) {
      const _Float16* A = (const _Float16*)Av;
#pragma unroll
      for (int t = 0; t < 2; ++t)
        async_load16(A + (size_t)(rowbase + (w * 2 + t) * 16 + brow) * K + k0 + bcol,
                     &As[(w * 2 + t) * 512]);
    } else {
      const float* A = (const float*)Av;
#pragma unroll
      for (int i = 0; i < 4; ++i) {
        const int f = tid + i * 256;
        const int r = f >> 3, c4 = f & 7;
        const float4 v = *(const float4*)(A + (size_t)(rowbase + r) * K + k0 + c4 * 4);
        h16x4 o = {(_Float16)v.x, (_Float16)v.y, (_Float16)v.z, (_Float16)v.w};
        *(h16x4*)&As[r * 32 + c4 * 4] = o;
      }
    }
#pragma unroll
    for (int t = 0; t < 2; ++t)
      async_load16(Bw + (size_t)(colbase + (w * 2 + t) * 16 + brow) * K + k0 + bcol,
                   &Bs[(w * 2 + t) * 512]);
    __syncthreads();

    h16x8 af[4], bfr[4];
#pragma unroll
    for (int mt = 0; mt < 4; ++mt)
      af[mt] = *(const h16x8*)&As[(wm * 64 + mt * 16 + m16) * 32 + q * 8];
#pragma unroll
    for (int nt = 0; nt < 4; ++nt)
      bfr[nt] = *(const h16x8*)&Bs[(wn * 64 + nt * 16 + m16) * 32 + q * 8];
#pragma unroll
    for (int mt = 0; mt < 4; ++mt)
#pragma unroll
      for (int nt = 0; nt < 4; ++nt)
        acc[mt][nt] = __builtin_amdgcn_mfma_f32_16x16x32_f16(af[mt], bfr[nt], acc[mt][nt], 0, 0, 0);
    __syncthreads();
  }

#pragma unroll
  for (int mt = 0; mt < 4; ++mt) {
#pragma unroll
    for (int nt = 0; nt < 4; ++nt) {
      const int col = colbase + wn * 64 + nt * 16 + m16;
#pragma unroll
      for (int r = 0; r < 4; ++r) {
        const int row = rowbase + wm * 64 + mt * 16 + q * 4 + r;
        if constexpr (OF32)
          ((float*)Cv)[(size_t)row * N + col] = acc[mt][nt][r];
        else
          ((_Float16*)Cv)[(size_t)row * N + col] = (_Float16)acc[mt][nt][r];
      }
    }
  }
}

// weights fp32 -> fp16 (4 matrices of 1024x1024, contiguous dst)
__global__ __launch_bounds__(256) void k_cvt_w(const float* __restrict__ Wq,
                                               const float* __restrict__ Wk,
                                               const float* __restrict__ Wv,
                                               const float* __restrict__ Wo,
                                               _Float16* __restrict__ dst) {
  const float* src;
  switch (blockIdx.y) {
    case 0: src = Wq; break;
    case 1: src = Wk; break;
    case 2: src = Wv; break;
    default: src = Wo; break;
  }
  _Float16* d = dst + (size_t)blockIdx.y * (1024 * 1024);
  const int idx = blockIdx.x * 256 + threadIdx.x;
  const float4 v = ((const float4*)src)[idx];
  h16x4 o = {(_Float16)v.x, (_Float16)v.y, (_Float16)v.z, (_Float16)v.w};
  ((h16x4*)d)[idx] = o;
}

// activations fp32 -> fp16 (3 matrices of 16384x1024, contiguous dst)
__global__ __launch_bounds__(256) void k_cvt_a(const float* __restrict__ q,
                                               const float* __restrict__ k,
                                               const float* __restrict__ v,
                                               _Float16* __restrict__ dst) {
  const float* src = (blockIdx.y == 0) ? q : (blockIdx.y == 1) ? k : v;
  _Float16* d = dst + (size_t)blockIdx.y * ((size_t)16384 * 1024);
  const size_t idx = (size_t)blockIdx.x * 256 + threadIdx.x;
  const float4 vv = ((const float4*)src)[idx];
  h16x4 o = {(_Float16)vv.x, (_Float16)vv.y, (_Float16)vv.z, (_Float16)vv.w};
  ((h16x4*)d)[idx] = o;
}

__global__ __launch_bounds__(256) void k_gemm_qkv_f16(const _Float16* __restrict__ xf,
                                                      const _Float16* __restrict__ Wf,
                                                      const float* __restrict__ bq,
                                                      const float* __restrict__ bk,
                                                      const float* __restrict__ bv,
                                                      _Float16* __restrict__ proj) {
  constexpr size_t MW = 1024 * 1024, MA = (size_t)16384 * 1024;
  const int y = blockIdx.y;
  const float* bias = (y == 0) ? bq : (y == 1) ? bk : bv;
  gemm_core<0, false>(xf + y * MA, Wf + y * MW, bias, proj + y * MA);
}

__global__ __launch_bounds__(256) void k_gemm_qkv_f32(const float* __restrict__ q,
                                                      const float* __restrict__ k,
                                                      const float* __restrict__ v,
                                                      const _Float16* __restrict__ Wf,
                                                      const float* __restrict__ bq,
                                                      const float* __restrict__ bk,
                                                      const float* __restrict__ bv,
                                                      _Float16* __restrict__ proj) {
  constexpr size_t MW = 1024 * 1024, MA = (size_t)16384 * 1024;
  const int y = blockIdx.y;
  const float* A    = (y == 0) ? q  : (y == 1) ? k  : v;
  const float* bias = (y == 0) ? bq : (y == 1) ? bk : bv;
  gemm_core<1, false>(A, Wf + y * MW, bias, proj + y * MA);
}

__global__ __launch_bounds__(256) void k_gemm_out(const _Float16* __restrict__ ao,
                                                  const _Float16* __restrict__ Wof,
                                                  const float* __restrict__ bo,
                                                  float* __restrict__ C) {
  gemm_core<0, true>(ao, Wof, bo, C);
}

// ---------------------------------------------------------------------------
// Per-position local attention. One WAVE per position; lane i owns score row i.
// k/v rows in LDS fp32 (row stride 20 floats: 16B-aligned, spreads write banks);
// all j-loop LDS reads are wave-uniform -> broadcast, conflict-free.
// Softmax entirely per-lane in registers: no cross-lane ops.
// ---------------------------------------------------------------------------
__global__ __launch_bounds__(256) void k_attn(const _Float16* __restrict__ qp,
                                              const _Float16* __restrict__ kp,
                                              const _Float16* __restrict__ vp,
                                              _Float16* __restrict__ op) {
  constexpr int RS = 20;  // floats per row (16 data + 4 pad)
  __shared__ __align__(16) float ks[4][64 * RS];
  __shared__ __align__(16) float vs[4][64 * RS];
  const int w    = threadIdx.x >> 6;
  const int lane = threadIdx.x & 63;
  const size_t base = ((size_t)blockIdx.x * 4 + w) * 1024;

  float qr[16];
  {
    h16x8 q0 = *(const h16x8*)(qp + base + lane * 16);
    h16x8 q1 = *(const h16x8*)(qp + base + lane * 16 + 8);
    h16x8 k0 = *(const h16x8*)(kp + base + lane * 16);
    h16x8 k1 = *(const h16x8*)(kp + base + lane * 16 + 8);
    h16x8 v0 = *(const h16x8*)(vp + base + lane * 16);
    h16x8 v1 = *(const h16x8*)(vp + base + lane * 16 + 8);
    f32x4 t;
#pragma unroll
    for (int c = 0; c < 2; ++c) {
#pragma unroll
      for (int e = 0; e < 4; ++e) t[e] = (float)k0[c * 4 + e];
      *(f32x4*)&ks[w][lane * RS + c * 4] = t;
#pragma unroll
      for (int e = 0; e < 4; ++e) t[e] = (float)k1[c * 4 + e];
      *(f32x4*)&ks[w][lane * RS + 8 + c * 4] = t;
#pragma unroll
      for (int e = 0; e < 4; ++e) t[e] = (float)v0[c * 4 + e];
      *(f32x4*)&vs[w][lane * RS + c * 4] = t;
#pragma unroll
      for (int e = 0; e < 4; ++e) t[e] = (float)v1[c * 4 + e];
      *(f32x4*)&vs[w][lane * RS + 8 + c * 4] = t;
    }
#pragma unroll
    for (int e = 0; e < 8; ++e) {
      qr[e] = (float)q0[e];
      qr[8 + e] = (float)q1[e];
    }
  }
  __syncthreads();

  const float* __restrict__ krow = ks[w];
  const float* __restrict__ vrow = vs[w];

  float s[64];
  float mx = -3.0e38f;
#pragma unroll
  for (int j = 0; j < 64; ++j) {
    float a = 0.f;
#pragma unroll
    for (int c = 0; c < 4; ++c) {
      const f32x4 kv = *(const f32x4*)&krow[j * RS + c * 4];
      a += qr[c * 4 + 0] * kv[0] + qr[c * 4 + 1] * kv[1] +
           qr[c * 4 + 2] * kv[2] + qr[c * 4 + 3] * kv[3];
    }
    s[j] = a * 32.0f;  // reference multiplies by sqrt(D)=32
    mx = fmaxf(mx, s[j]);
  }

  float o[16];
#pragma unroll
  for (int h = 0; h < 16; ++h) o[h] = 0.f;
  float sum = 0.f;
#pragma unroll
  for (int j = 0; j < 64; ++j) {
    const float p = __expf(s[j] - mx);
    sum += p;
#pragma unroll
    for (int c = 0; c < 4; ++c) {
      const f32x4 vv = *(const f32x4*)&vrow[j * RS + c * 4];
      o[c * 4 + 0] += p * vv[0]; o[c * 4 + 1] += p * vv[1];
      o[c * 4 + 2] += p * vv[2]; o[c * 4 + 3] += p * vv[3];
    }
  }
  const float inv = 1.0f / sum;

  h16x8 w0, w1;
#pragma unroll
  for (int e = 0; e < 8; ++e) {
    w0[e] = (_Float16)(o[e] * inv);
    w1[e] = (_Float16)(o[8 + e] * inv);
  }
  *(h16x8*)(op + base + lane * 16) = w0;
  *(h16x8*)(op + base + lane * 16 + 8) = w1;
}

extern "C" void kernel_launch(void* const* d_in, const int* in_sizes, int n_in,
                              void* d_out, int out_size, void* d_ws, size_t ws_size,
                              hipStream_t stream) {
  const float* query = (const float*)d_in[0];
  const float* key_  = (const float*)d_in[1];
  const float* value = (const float*)d_in[2];
  const float* Wq    = (const float*)d_in[3];
  const float* bq    = (const float*)d_in[4];
  const float* Wk    = (const float*)d_in[5];
  const float* bk    = (const float*)d_in[6];
  const float* Wv    = (const float*)d_in[7];
  const float* bv    = (const float*)d_in[8];
  const float* Wo    = (const float*)d_in[9];
  const float* bo    = (const float*)d_in[10];

  constexpr size_t MW = 1024 * 1024;
  constexpr size_t MA = (size_t)16384 * 1024;

  _Float16* Wf = (_Float16*)d_ws;  // 4*MW fp16 = 8 MB
  const size_t needA = (4 * MW + 6 * MA) * sizeof(_Float16);  // 200 MB

  k_cvt_w<<<dim3(1024, 4), 256, 0, stream>>>(Wq, Wk, Wv, Wo, Wf);

  if (ws_size >= needA) {
    _Float16* xf   = Wf + 4 * MW;  // converted q,k,v inputs: 96 MB
    _Float16* proj = xf + 3 * MA;  // projected q,k,v: 96 MB
    _Float16* ao   = xf;           // alias: inputs dead after QKV GEMM
    k_cvt_a<<<dim3(16384, 3), 256, 0, stream>>>(query, key_, value, xf);
    k_gemm_qkv_f16<<<dim3(1024, 3), 256, 0, stream>>>(xf, Wf, bq, bk, bv, proj);
    k_attn<<<4096, 256, 0, stream>>>(proj, proj + MA, proj + 2 * MA, ao);
    k_gemm_out<<<1024, 256, 0, stream>>>(ao, Wf + 3 * MW, bo, (float*)d_out);
  } else {
    _Float16* proj = Wf + 4 * MW;
    _Float16* ao   = proj + 3 * MA;
    k_gemm_qkv_f32<<<dim3(1024, 3), 256, 0, stream>>>(query, key_, value, Wf,
                                                      bq, bk, bv, proj);
    k_attn<<<4096, 256, 0, stream>>>(proj, proj + MA, proj + 2 * MA, ao);
    k_gemm_out<<<1024, 256, 0, stream>>>(ao, Wf + 3 * MW, bo, (float*)d_out);
  }
}